// Round 1
// baseline (138.469 us; speedup 1.0000x reference)
//
#include <hip/hip_runtime.h>

constexpr int KN    = 32;
constexpr int NPAIR = KN * (KN - 1) / 2;   // 496
constexpr int PPB   = 4;                   // particles per block (1 wave each)

__global__ __launch_bounds__(256) void sw_energy_kernel(
    const int*   __restrict__ pc,
    const float* __restrict__ coords,
    const int*   __restrict__ nbr,
    const float* __restrict__ sA,
    const float* __restrict__ sB,
    const float* __restrict__ sP,
    const float* __restrict__ sQ,
    const float* __restrict__ sSigma,
    const float* __restrict__ sGamma,
    const float* __restrict__ sCutoff,
    const float* __restrict__ sLam,
    const float* __restrict__ sCosb0,
    double* __restrict__ ws,
    int n)
{
    __shared__ float  sh[PPB][6][KN];   // dx,dy,dz,rsq,g,invr per neighbor
    __shared__ double sred[PPB];

    const int tid  = threadIdx.x;
    const int wv   = tid >> 6;          // wave within block
    const int lane = tid & 63;
    const int p    = blockIdx.x * PPB + wv;
    const bool active = (p < n);

    const float A     = *sA;
    const float Bc    = *sB;
    const float pexp  = *sP;
    const float qexp  = *sQ;
    const float sigma = *sSigma;
    const float gamma = *sGamma;
    const float cut   = *sCutoff;
    const float lam   = *sLam;
    const float cosb0 = *sCosb0;

    double acc = 0.0;

    // ---- phase 1: per-neighbor precompute (lanes 0..31) + E2 term ----
    if (active && lane < KN) {
        const float xi = coords[3 * p + 0];
        const float yi = coords[3 * p + 1];
        const float zi = coords[3 * p + 2];
        const int   nb = nbr[p * KN + lane];
        const float dx = coords[3 * nb + 0] - xi;
        const float dy = coords[3 * nb + 1] - yi;
        const float dz = coords[3 * nb + 2] - zi;
        const float s  = dx * dx + dy * dy + dz * dz + 1e-12f;
        const float r  = sqrtf(s);
        const float ir = 1.0f / r;
        const float g  = expf(gamma / (r - cut));   // e3 factor: exp(g/(r1-c)+g/(r2-c)) = g1*g2

        sh[wv][0][lane] = dx;
        sh[wv][1][lane] = dy;
        sh[wv][2][lane] = dz;
        sh[wv][3][lane] = s;     // rij^2 (incl. EPS), matches r1*r1 within rounding
        sh[wv][4][lane] = g;
        sh[wv][5][lane] = ir;

        if (r < cut) {
            const float sig_r = sigma / r;
            const float e2 = A * (Bc * powf(sig_r, pexp) - powf(sig_r, qexp))
                               * expf(sigma / (r - cut));
            acc += 0.5 * (double)e2;
        }
    }
    __syncthreads();

    // ---- phase 2: all 64 lanes sweep the 496 (jj<kk) pairs ----
    if (active) {
        for (int t = lane; t < NPAIR; t += 64) {
            // decode flat upper-triangle index t -> (jj, kk)
            const float disc = (float)((2 * KN - 1) * (2 * KN - 1) - 8 * t); // 3969 - 8t
            int jj = (int)((63.0f - sqrtf(disc)) * 0.5f);
            if (jj < 0) jj = 0;
            if (jj > KN - 2) jj = KN - 2;
            int off = (jj * (2 * KN - 1 - jj)) >> 1;
            while (jj < KN - 2) {
                const int offn = ((jj + 1) * (2 * KN - 2 - jj)) >> 1;
                if (offn <= t) { jj++; off = offn; } else break;
            }
            while (off > t) { jj--; off = (jj * (2 * KN - 1 - jj)) >> 1; }
            const int kk = t - off + jj + 1;

            const float x1 = sh[wv][0][jj], x2 = sh[wv][0][kk];
            const float y1 = sh[wv][1][jj], y2 = sh[wv][1][kk];
            const float z1 = sh[wv][2][jj], z2 = sh[wv][2][kk];
            const float q1 = sh[wv][3][jj], q2 = sh[wv][3][kk];
            const float g1 = sh[wv][4][jj], g2 = sh[wv][4][kk];
            const float i1 = sh[wv][5][jj], i2 = sh[wv][5][kk];

            const float ddx  = x2 - x1;
            const float ddy  = y2 - y1;
            const float ddz  = z2 - z1;
            const float r3sq = ddx * ddx + ddy * ddy + ddz * ddz;
            const float cosb = (q1 + q2 - r3sq) * (0.5f * i1 * i2);
            const float dcb  = cosb - cosb0;
            const float e3   = lam * (g1 * g2) * (dcb * dcb);
            acc += (double)e3;
        }
        if (pc[p] != 1) acc = 0.0;   // weight w
    }

    // ---- reduction: wave shuffle -> block -> one atomic per block ----
    for (int o = 32; o > 0; o >>= 1) acc += __shfl_down(acc, o, 64);
    if (lane == 0) sred[wv] = acc;
    __syncthreads();
    if (tid == 0) {
        const double s = sred[0] + sred[1] + sred[2] + sred[3];
        atomicAdd(ws, s);
    }
}

__global__ void sw_finalize_kernel(const double* __restrict__ ws,
                                   float* __restrict__ out)
{
    out[0] = (float)ws[0];
}

extern "C" void kernel_launch(void* const* d_in, const int* in_sizes, int n_in,
                              void* d_out, int out_size, void* d_ws, size_t ws_size,
                              hipStream_t stream) {
    const int*   pc     = (const int*)  d_in[0];
    const float* coords = (const float*)d_in[1];
    // d_in[2] = num_neighbors (unused by reference)
    const int*   nbr    = (const int*)  d_in[3];
    const float* sA     = (const float*)d_in[4];
    const float* sB     = (const float*)d_in[5];
    const float* sP     = (const float*)d_in[6];
    const float* sQ     = (const float*)d_in[7];
    const float* sSigma = (const float*)d_in[8];
    const float* sGamma = (const float*)d_in[9];
    const float* sCut   = (const float*)d_in[10];
    const float* sLam   = (const float*)d_in[11];
    const float* sCosb0 = (const float*)d_in[12];

    const int n = in_sizes[0];

    double* ws  = (double*)d_ws;
    float*  out = (float*)d_out;

    hipMemsetAsync(ws, 0, sizeof(double), stream);

    const int blocks = (n + PPB - 1) / PPB;
    sw_energy_kernel<<<blocks, 256, 0, stream>>>(
        pc, coords, nbr, sA, sB, sP, sQ, sSigma, sGamma, sCut, sLam, sCosb0,
        ws, n);

    sw_finalize_kernel<<<1, 1, 0, stream>>>(ws, out);
}

// Round 2
// 77.632 us; speedup vs baseline: 1.7837x; 1.7837x over previous
//
#include <hip/hip_runtime.h>

constexpr int KN  = 32;
constexpr int WPB = 4;          // waves per block
constexpr int PPW = 2;          // particles per wave (one per 32-lane half)
constexpr int PPB = WPB * PPW;  // 8 particles per block

__global__ __launch_bounds__(256) void sw_energy_kernel(
    const int*   __restrict__ pc,
    const float* __restrict__ coords,
    const int*   __restrict__ nbr,
    const float* __restrict__ sA,
    const float* __restrict__ sB,
    const float* __restrict__ sP,
    const float* __restrict__ sQ,
    const float* __restrict__ sSigma,
    const float* __restrict__ sGamma,
    const float* __restrict__ sCutoff,
    const float* __restrict__ sLam,
    const float* __restrict__ sCosb0,
    double* __restrict__ ws,
    int n)
{
    __shared__ double sred[WPB];

    const int tid  = threadIdx.x;
    const int wv   = tid >> 6;
    const int lane = tid & 63;
    const int half = lane >> 5;         // which particle in this wave
    const int slot = lane & 31;         // neighbor slot
    const int p    = blockIdx.x * PPB + wv * PPW + half;
    const bool active = (p < n);

    const float A     = *sA;
    const float Bc    = *sB;
    const float pexp  = *sP;
    const float qexp  = *sQ;
    const float sigma = *sSigma;
    const float gamma = *sGamma;
    const float cut   = *sCutoff;
    const float lam   = *sLam;
    const float cosb0 = *sCosb0;
    const float sqlam = sqrtf(lam);

    // ---- phase 1: per-neighbor precompute, all state in registers ----
    float ux = 0.f, uy = 0.f, uz = 0.f, gs = 0.f, w = 0.f;
    double e2d = 0.0;
    if (active) {
        const float xi = coords[3 * p + 0];
        const float yi = coords[3 * p + 1];
        const float zi = coords[3 * p + 2];
        const int   nb = nbr[p * KN + slot];
        const float dx = coords[3 * nb + 0] - xi;
        const float dy = coords[3 * nb + 1] - yi;
        const float dz = coords[3 * nb + 2] - zi;
        const float s  = dx * dx + dy * dy + dz * dz + 1e-12f;
        const float ir = rsqrtf(s);
        const float r  = s * ir;
        const float irc = 1.0f / (r - cut);        // negative (r < cutoff here)
        gs = sqlam * __expf(gamma * irc);          // sqrt(lam)*exp(gamma/(r-cut))
        ux = dx * ir; uy = dy * ir; uz = dz * ir;  // unit vector

        if (r < cut) {
            const float sig_r = sigma * ir;
            const float e2 = A * (Bc * __powf(sig_r, pexp) - __powf(sig_r, qexp))
                               * __expf(sigma * irc);
            e2d = 0.5 * (double)e2;
        }
        w = (pc[p] == 1) ? 1.0f : 0.0f;
    }

    // ---- phase 2: register-rotation over the 496 unordered pairs ----
    // pair (slot, (slot+d)&31) for d=1..15 (all distinct), d=16 weight 1/2
    float acc3a = 0.f, acc3b = 0.f;
    const int base = lane & 32;

#pragma unroll
    for (int d = 1; d <= 15; d += 2) {
        {
            const int pl = base | ((lane + d) & 31);
            const float vx = __shfl(ux, pl, 64);
            const float vy = __shfl(uy, pl, 64);
            const float vz = __shfl(uz, pl, 64);
            const float vg = __shfl(gs, pl, 64);
            const float c   = fmaf(ux, vx, fmaf(uy, vy, uz * vz));
            const float dcb = c - cosb0;
            const float m   = gs * vg;
            acc3a = fmaf(m * dcb, dcb, acc3a);
        }
        {
            const int pl = base | ((lane + d + 1) & 31);
            const float vx = __shfl(ux, pl, 64);
            const float vy = __shfl(uy, pl, 64);
            const float vz = __shfl(uz, pl, 64);
            const float vg = __shfl(gs, pl, 64);
            const float c   = fmaf(ux, vx, fmaf(uy, vy, uz * vz));
            const float dcb = c - cosb0;
            const float m   = gs * vg;
            acc3b = fmaf(m * dcb, dcb, acc3b);
        }
    }
    {   // d = 16: each pair computed by both lanes -> half weight
        const int pl = base | ((lane + 16) & 31);
        const float vx = __shfl(ux, pl, 64);
        const float vy = __shfl(uy, pl, 64);
        const float vz = __shfl(uz, pl, 64);
        const float vg = __shfl(gs, pl, 64);
        const float c   = fmaf(ux, vx, fmaf(uy, vy, uz * vz));
        const float dcb = c - cosb0;
        const float m   = 0.5f * gs * vg;
        acc3a = fmaf(m * dcb, dcb, acc3a);
    }

    // ---- per-lane total, weighted; reduce in double ----
    double tot = (double)w * ((double)(acc3a + acc3b) + e2d);
    for (int o = 32; o > 0; o >>= 1) tot += __shfl_down(tot, o, 64);

    if (lane == 0) sred[wv] = tot;
    __syncthreads();
    if (tid == 0) {
        atomicAdd(ws, sred[0] + sred[1] + sred[2] + sred[3]);
    }
}

__global__ void sw_finalize_kernel(const double* __restrict__ ws,
                                   float* __restrict__ out)
{
    out[0] = (float)ws[0];
}

extern "C" void kernel_launch(void* const* d_in, const int* in_sizes, int n_in,
                              void* d_out, int out_size, void* d_ws, size_t ws_size,
                              hipStream_t stream) {
    const int*   pc     = (const int*)  d_in[0];
    const float* coords = (const float*)d_in[1];
    // d_in[2] = num_neighbors (constant K=32, unused by reference math)
    const int*   nbr    = (const int*)  d_in[3];
    const float* sA     = (const float*)d_in[4];
    const float* sB     = (const float*)d_in[5];
    const float* sP     = (const float*)d_in[6];
    const float* sQ     = (const float*)d_in[7];
    const float* sSigma = (const float*)d_in[8];
    const float* sGamma = (const float*)d_in[9];
    const float* sCut   = (const float*)d_in[10];
    const float* sLam   = (const float*)d_in[11];
    const float* sCosb0 = (const float*)d_in[12];

    const int n = in_sizes[0];

    double* ws  = (double*)d_ws;
    float*  out = (float*)d_out;

    hipMemsetAsync(ws, 0, sizeof(double), stream);

    const int blocks = (n + PPB - 1) / PPB;
    sw_energy_kernel<<<blocks, 256, 0, stream>>>(
        pc, coords, nbr, sA, sB, sP, sQ, sSigma, sGamma, sCut, sLam, sCosb0,
        ws, n);

    sw_finalize_kernel<<<1, 1, 0, stream>>>(ws, out);
}

// Round 3
// 27.401 us; speedup vs baseline: 5.0534x; 2.8332x over previous
//
#include <hip/hip_runtime.h>

constexpr int KN  = 32;
constexpr int WPB = 4;          // waves per block
constexpr int PPW = 2;          // particles per wave (one per 32-lane half)
constexpr int PPB = WPB * PPW;  // 8 particles per block
constexpr int NSLOT = 64;       // spread slots for the final atomic

// v + (v permuted by DPP ctrl) -- pure VALU cross-lane add
template <int CTRL>
__device__ __forceinline__ float dpp_add(float v) {
    int p = __builtin_amdgcn_update_dpp(0, __float_as_int(v), CTRL, 0xF, 0xF, true);
    return v + __int_as_float(p);
}

// full sum over each 32-lane group; result in all lanes of the group
__device__ __forceinline__ float red32(float v) {
    v = dpp_add<0xB1>(v);    // quad_perm [1,0,3,2]  : xor 1
    v = dpp_add<0x4E>(v);    // quad_perm [2,3,0,1]  : xor 2
    v = dpp_add<0x124>(v);   // row_ror:4  (within 16)
    v = dpp_add<0x128>(v);   // row_ror:8  (within 16) -> full 16-row sum
    int p = __builtin_amdgcn_ds_swizzle(__float_as_int(v), 0x401F); // xor 16 (within 32)
    return v + __int_as_float(p);
}

__global__ __launch_bounds__(256) void sw_energy_kernel(
    const int*   __restrict__ pc,
    const float* __restrict__ coords,
    const int*   __restrict__ nbr,
    const float* __restrict__ sA,
    const float* __restrict__ sB,
    const float* __restrict__ sP,
    const float* __restrict__ sQ,
    const float* __restrict__ sSigma,
    const float* __restrict__ sGamma,
    const float* __restrict__ sCutoff,
    const float* __restrict__ sLam,
    const float* __restrict__ sCosb0,
    double* __restrict__ ws,
    int n)
{
    __shared__ double sred[WPB];

    const int tid  = threadIdx.x;
    const int wv   = tid >> 6;
    const int lane = tid & 63;
    const int half = lane >> 5;         // which particle in this wave
    const int slot = lane & 31;         // neighbor slot
    const int p    = blockIdx.x * PPB + wv * PPW + half;
    const bool active = (p < n);

    const float A     = *sA;
    const float Bc    = *sB;
    const float pexp  = *sP;
    const float qexp  = *sQ;
    const float sigma = *sSigma;
    const float gamma = *sGamma;
    const float cut   = *sCutoff;
    const float lam   = *sLam;
    const float cosb0 = *sCosb0;
    const float sqlam = sqrtf(lam);

    // ---- per-neighbor: unit vector u, g = sqrt(lam)*exp(gamma/(r-cut)), e2 ----
    float ux = 0.f, uy = 0.f, uz = 0.f, g = 0.f, e2 = 0.f, w = 0.f;
    if (active) {
        const float xi = coords[3 * p + 0];
        const float yi = coords[3 * p + 1];
        const float zi = coords[3 * p + 2];
        const int   nb = nbr[p * KN + slot];
        const float dx = coords[3 * nb + 0] - xi;
        const float dy = coords[3 * nb + 1] - yi;
        const float dz = coords[3 * nb + 2] - zi;
        const float s  = dx * dx + dy * dy + dz * dz + 1e-12f;
        const float ir = rsqrtf(s);
        const float r  = s * ir;
        const float irc = 1.0f / (r - cut);      // negative (r < cutoff)
        g  = sqlam * __expf(gamma * irc);
        ux = dx * ir; uy = dy * ir; uz = dz * ir;

        const float sig_r = sigma * ir;
        const float lg = __log2f(sig_r);
        e2 = A * (Bc * exp2f(pexp * lg) - exp2f(qexp * lg)) * __expf(sigma * irc);
        if (!(r < cut)) e2 = 0.f;
        w = (pc[p] == 1) ? 1.f : 0.f;
    }

    // ---- per-lane moment components (11) + e2 ----
    const float g2  = g * g;
    const float tx  = g * ux, ty = g * uy, tz = g * uz;
    const float mxx = tx * ux, myy = ty * uy, mzz = tz * uz;
    const float mxy = tx * uy, mxz = tx * uz, myz = ty * uz;

    // ---- reduce 12 values over the 32-lane group ----
    const float S1  = red32(g);
    const float G2  = red32(g2);
    const float Vx  = red32(tx),  Vy  = red32(ty),  Vz  = red32(tz);
    const float Mxx = red32(mxx), Myy = red32(myy), Mzz = red32(mzz);
    const float Mxy = red32(mxy), Mxz = red32(mxz), Myz = red32(myz);
    const float E2s = red32(e2);

    // ---- closed-form three-body energy per particle ----
    const float trM2 = Mxx * Mxx + Myy * Myy + Mzz * Mzz
                     + 2.f * (Mxy * Mxy + Mxz * Mxz + Myz * Myz);
    const float V2  = Vx * Vx + Vy * Vy + Vz * Vz;
    const float omc = 1.f - cosb0;
    const float E3  = 0.5f * (trM2 - 2.f * cosb0 * V2 + cosb0 * cosb0 * S1 * S1
                              - omc * omc * G2);
    const float Ep  = w * (E3 + 0.5f * E2s);   // uniform within each 32-half

    // ---- wave total: lane 0 combines both halves ----
    const float Eb = __shfl(Ep, 32, 64);       // particle B's energy (from lane 32)
    if (lane == 0) sred[wv] = (double)Ep + (double)Eb;
    __syncthreads();
    if (tid == 0) {
        atomicAdd(&ws[blockIdx.x & (NSLOT - 1)],
                  sred[0] + sred[1] + sred[2] + sred[3]);
    }
}

__global__ void sw_finalize_kernel(const double* __restrict__ ws,
                                   float* __restrict__ out)
{
    const int lane = threadIdx.x;
    double v = ws[lane];
    for (int o = 32; o > 0; o >>= 1) v += __shfl_down(v, o, 64);
    if (lane == 0) out[0] = (float)v;
}

extern "C" void kernel_launch(void* const* d_in, const int* in_sizes, int n_in,
                              void* d_out, int out_size, void* d_ws, size_t ws_size,
                              hipStream_t stream) {
    const int*   pc     = (const int*)  d_in[0];
    const float* coords = (const float*)d_in[1];
    // d_in[2] = num_neighbors (constant K=32, unused by reference math)
    const int*   nbr    = (const int*)  d_in[3];
    const float* sA     = (const float*)d_in[4];
    const float* sB     = (const float*)d_in[5];
    const float* sP     = (const float*)d_in[6];
    const float* sQ     = (const float*)d_in[7];
    const float* sSigma = (const float*)d_in[8];
    const float* sGamma = (const float*)d_in[9];
    const float* sCut   = (const float*)d_in[10];
    const float* sLam   = (const float*)d_in[11];
    const float* sCosb0 = (const float*)d_in[12];

    const int n = in_sizes[0];

    double* ws  = (double*)d_ws;
    float*  out = (float*)d_out;

    hipMemsetAsync(ws, 0, NSLOT * sizeof(double), stream);

    const int blocks = (n + PPB - 1) / PPB;
    sw_energy_kernel<<<blocks, 256, 0, stream>>>(
        pc, coords, nbr, sA, sB, sP, sQ, sSigma, sGamma, sCut, sLam, sCosb0,
        ws, n);

    sw_finalize_kernel<<<1, 64, 0, stream>>>(ws, out);
}

// Round 4
// 17.454 us; speedup vs baseline: 7.9336x; 1.5699x over previous
//
#include <hip/hip_runtime.h>

constexpr int KN  = 32;
constexpr int WPB = 4;           // waves per block
constexpr int PPW = 4;           // particles per wave (2 halves x 2 chains/lane)
constexpr int PPB = WPB * PPW;   // 16 particles per block

// v + (v permuted by DPP ctrl) -- pure VALU cross-lane add
template <int CTRL>
__device__ __forceinline__ float dpp_add(float v) {
    int p = __builtin_amdgcn_update_dpp(0, __float_as_int(v), CTRL, 0xF, 0xF, true);
    return v + __int_as_float(p);
}

// full sum over each 32-lane group; result in all lanes of the group
__device__ __forceinline__ float red32(float v) {
    v = dpp_add<0xB1>(v);    // quad_perm xor1
    v = dpp_add<0x4E>(v);    // quad_perm xor2
    v = dpp_add<0x124>(v);   // row_ror:4
    v = dpp_add<0x128>(v);   // row_ror:8 -> full 16-row sum
    int p = __builtin_amdgcn_ds_swizzle(__float_as_int(v), 0x401F); // xor16 within 32
    return v + __int_as_float(p);
}

__global__ __launch_bounds__(256) void sw_energy_kernel(
    const int*   __restrict__ pc,
    const float* __restrict__ coords,
    const int*   __restrict__ nbr,
    const float* __restrict__ sA,
    const float* __restrict__ sB,
    const float* __restrict__ sP,
    const float* __restrict__ sQ,
    const float* __restrict__ sSigma,
    const float* __restrict__ sGamma,
    const float* __restrict__ sCutoff,
    const float* __restrict__ sLam,
    const float* __restrict__ sCosb0,
    double* __restrict__ ws,
    int n)
{
    __shared__ double sred[WPB];

    const int tid  = threadIdx.x;
    const int wv   = tid >> 6;
    const int lane = tid & 63;
    const int half = lane >> 5;
    const int slot = lane & 31;
    const int p0   = blockIdx.x * PPB + wv * PPW + half;     // chain 0 particle
    const int p1   = p0 + 2;                                 // chain 1 particle
    const bool a0  = (p0 < n);
    const bool a1  = (p1 < n);

    const float A     = *sA;
    const float Bc    = *sB;
    const float pexp  = *sP;
    const float qexp  = *sQ;
    const float sigma = *sSigma;
    const float gamma = *sGamma;
    const float cut   = *sCutoff;
    const float lam   = *sLam;
    const float cosb0 = *sCosb0;
    const float sqlam = sqrtf(lam);

    // ---- two independent per-neighbor chains per lane ----
    float ux0=0.f, uy0=0.f, uz0=0.f, g0=0.f, e20=0.f, w0=0.f;
    float ux1=0.f, uy1=0.f, uz1=0.f, g1=0.f, e21=0.f, w1=0.f;

    if (a0) {
        const float xi = coords[3*p0+0], yi = coords[3*p0+1], zi = coords[3*p0+2];
        const int   nb = nbr[p0 * KN + slot];
        const float dx = coords[3*nb+0] - xi;
        const float dy = coords[3*nb+1] - yi;
        const float dz = coords[3*nb+2] - zi;
        const float s  = dx*dx + dy*dy + dz*dz + 1e-12f;
        const float ir = rsqrtf(s);
        const float r  = s * ir;
        const float irc = 1.0f / (r - cut);
        g0  = sqlam * __expf(gamma * irc);
        ux0 = dx*ir; uy0 = dy*ir; uz0 = dz*ir;
        const float lg = __log2f(sigma * ir);
        e20 = A * (Bc * exp2f(pexp * lg) - exp2f(qexp * lg)) * __expf(sigma * irc);
        if (!(r < cut)) e20 = 0.f;
        w0 = (pc[p0] == 1) ? 1.f : 0.f;
    }
    if (a1) {
        const float xi = coords[3*p1+0], yi = coords[3*p1+1], zi = coords[3*p1+2];
        const int   nb = nbr[p1 * KN + slot];
        const float dx = coords[3*nb+0] - xi;
        const float dy = coords[3*nb+1] - yi;
        const float dz = coords[3*nb+2] - zi;
        const float s  = dx*dx + dy*dy + dz*dz + 1e-12f;
        const float ir = rsqrtf(s);
        const float r  = s * ir;
        const float irc = 1.0f / (r - cut);
        g1  = sqlam * __expf(gamma * irc);
        ux1 = dx*ir; uy1 = dy*ir; uz1 = dz*ir;
        const float lg = __log2f(sigma * ir);
        e21 = A * (Bc * exp2f(pexp * lg) - exp2f(qexp * lg)) * __expf(sigma * irc);
        if (!(r < cut)) e21 = 0.f;
        w1 = (pc[p1] == 1) ? 1.f : 0.f;
    }

    // ---- moments + reductions (two interleaved independent trees) ----
    const float tx0 = g0*ux0, ty0 = g0*uy0, tz0 = g0*uz0;
    const float tx1 = g1*ux1, ty1 = g1*uy1, tz1 = g1*uz1;

    const float S1_0  = red32(g0);          const float S1_1  = red32(g1);
    const float G2_0  = red32(g0*g0);       const float G2_1  = red32(g1*g1);
    const float Vx0   = red32(tx0);         const float Vx1   = red32(tx1);
    const float Vy0   = red32(ty0);         const float Vy1   = red32(ty1);
    const float Vz0   = red32(tz0);         const float Vz1   = red32(tz1);
    const float Mxx0  = red32(tx0*ux0);     const float Mxx1  = red32(tx1*ux1);
    const float Myy0  = red32(ty0*uy0);     const float Myy1  = red32(ty1*uy1);
    const float Mzz0  = red32(tz0*uz0);     const float Mzz1  = red32(tz1*uz1);
    const float Mxy0  = red32(tx0*uy0);     const float Mxy1  = red32(tx1*uy1);
    const float Mxz0  = red32(tx0*uz0);     const float Mxz1  = red32(tx1*uz1);
    const float Myz0  = red32(ty0*uz0);     const float Myz1  = red32(ty1*uz1);
    const float E2s0  = red32(e20);         const float E2s1  = red32(e21);

    const float omc  = 1.f - cosb0;
    const float c0sq = cosb0 * cosb0;

    const float trM2_0 = Mxx0*Mxx0 + Myy0*Myy0 + Mzz0*Mzz0
                       + 2.f*(Mxy0*Mxy0 + Mxz0*Mxz0 + Myz0*Myz0);
    const float V2_0   = Vx0*Vx0 + Vy0*Vy0 + Vz0*Vz0;
    const float E3_0   = 0.5f*(trM2_0 - 2.f*cosb0*V2_0 + c0sq*S1_0*S1_0 - omc*omc*G2_0);

    const float trM2_1 = Mxx1*Mxx1 + Myy1*Myy1 + Mzz1*Mzz1
                       + 2.f*(Mxy1*Mxy1 + Mxz1*Mxz1 + Myz1*Myz1);
    const float V2_1   = Vx1*Vx1 + Vy1*Vy1 + Vz1*Vz1;
    const float E3_1   = 0.5f*(trM2_1 - 2.f*cosb0*V2_1 + c0sq*S1_1*S1_1 - omc*omc*G2_1);

    // energy of this lane's 32-group (uniform within the group)
    const float Eh = w0*(E3_0 + 0.5f*E2s0) + w1*(E3_1 + 0.5f*E2s1);

    // combine the two halves of the wave
    const float Eo = __shfl(Eh, lane ^ 32, 64);
    if (lane == 0) sred[wv] = (double)Eh + (double)Eo;
    __syncthreads();
    if (tid == 0) {
        ws[blockIdx.x] = sred[0] + sred[1] + sred[2] + sred[3];  // plain store
    }
}

__global__ __launch_bounds__(256) void sw_finalize_kernel(
    const double* __restrict__ ws, float* __restrict__ out, int nb)
{
    __shared__ double sred[4];
    const int tid = threadIdx.x;
    double acc = 0.0;
    for (int i = tid; i < nb; i += 256) acc += ws[i];
    for (int o = 32; o > 0; o >>= 1) acc += __shfl_down(acc, o, 64);
    if ((tid & 63) == 0) sred[tid >> 6] = acc;
    __syncthreads();
    if (tid == 0) out[0] = (float)(sred[0] + sred[1] + sred[2] + sred[3]);
}

extern "C" void kernel_launch(void* const* d_in, const int* in_sizes, int n_in,
                              void* d_out, int out_size, void* d_ws, size_t ws_size,
                              hipStream_t stream) {
    const int*   pc     = (const int*)  d_in[0];
    const float* coords = (const float*)d_in[1];
    // d_in[2] = num_neighbors (constant K=32, unused by reference math)
    const int*   nbr    = (const int*)  d_in[3];
    const float* sA     = (const float*)d_in[4];
    const float* sB     = (const float*)d_in[5];
    const float* sP     = (const float*)d_in[6];
    const float* sQ     = (const float*)d_in[7];
    const float* sSigma = (const float*)d_in[8];
    const float* sGamma = (const float*)d_in[9];
    const float* sCut   = (const float*)d_in[10];
    const float* sLam   = (const float*)d_in[11];
    const float* sCosb0 = (const float*)d_in[12];

    const int n = in_sizes[0];

    double* ws  = (double*)d_ws;
    float*  out = (float*)d_out;

    const int blocks = (n + PPB - 1) / PPB;   // 2500: every ws[b] overwritten
    sw_energy_kernel<<<blocks, 256, 0, stream>>>(
        pc, coords, nbr, sA, sB, sP, sQ, sSigma, sGamma, sCut, sLam, sCosb0,
        ws, n);

    sw_finalize_kernel<<<1, 256, 0, stream>>>(ws, out, blocks);
}

// Round 5
// 16.053 us; speedup vs baseline: 8.6259x; 1.0873x over previous
//
#include <hip/hip_runtime.h>

constexpr int KN  = 32;
constexpr int WPB = 4;           // waves per block
constexpr int PPW = 8;           // particles per wave: 4 groups x 2 chains
constexpr int PPB = WPB * PPW;   // 32 particles per block

// v + (v permuted by DPP ctrl) -- pure VALU cross-lane add
template <int CTRL>
__device__ __forceinline__ float dpp_add(float v) {
    int p = __builtin_amdgcn_update_dpp(0, __float_as_int(v), CTRL, 0xF, 0xF, true);
    return v + __int_as_float(p);
}

// full sum over each 16-lane group (DPP only, no LDS); result in all 16 lanes
__device__ __forceinline__ float red16(float v) {
    v = dpp_add<0xB1>(v);    // quad_perm xor1
    v = dpp_add<0x4E>(v);    // quad_perm xor2
    v = dpp_add<0x124>(v);   // row_ror:4
    v = dpp_add<0x128>(v);   // row_ror:8
    return v;
}

struct Mom { float S1,G2,Vx,Vy,Vz,Mxx,Myy,Mzz,Mxy,Mxz,Myz,E2; };

__device__ __forceinline__ Mom gather2(
    const float* __restrict__ coords, const int* __restrict__ nbr,
    int p, int sl, int n,
    float A, float Bc, float pexp, float qexp,
    float sigma, float gamma, float cut, float sqlam, bool fastpq)
{
    Mom m;
    if (p >= n) {
        m.S1=m.G2=m.Vx=m.Vy=m.Vz=m.Mxx=m.Myy=m.Mzz=m.Mxy=m.Mxz=m.Myz=m.E2=0.f;
        return m;
    }
    const float xi = coords[3*p+0], yi = coords[3*p+1], zi = coords[3*p+2];
    const int nb0 = nbr[p*KN + sl];
    const int nb1 = nbr[p*KN + sl + 16];

    const float ax = coords[3*nb0+0], ay = coords[3*nb0+1], az = coords[3*nb0+2];
    const float bx = coords[3*nb1+0], by = coords[3*nb1+1], bz = coords[3*nb1+2];

    const float dx0 = ax-xi, dy0 = ay-yi, dz0 = az-zi;
    const float dx1 = bx-xi, dy1 = by-yi, dz1 = bz-zi;

    const float s0 = dx0*dx0 + dy0*dy0 + dz0*dz0 + 1e-12f;
    const float s1 = dx1*dx1 + dy1*dy1 + dz1*dz1 + 1e-12f;
    const float ir0 = rsqrtf(s0), ir1 = rsqrtf(s1);
    const float r0 = s0*ir0,      r1 = s1*ir1;
    const float irc0 = 1.f/(r0-cut), irc1 = 1.f/(r1-cut);   // negative inside cutoff
    const float g0 = sqlam*__expf(gamma*irc0);
    const float g1 = sqlam*__expf(gamma*irc1);
    const float ux0=dx0*ir0, uy0=dy0*ir0, uz0=dz0*ir0;
    const float ux1=dx1*ir1, uy1=dy1*ir1, uz1=dz1*ir1;

    float e20, e21;
    if (fastpq) {            // p==4, q==0: (sig/r)^4 via 2 muls, (sig/r)^0 == 1
        const float sr0=sigma*ir0, sr1=sigma*ir1;
        const float q0=sr0*sr0, q1=sr1*sr1;
        e20 = A*(Bc*q0*q0 - 1.f)*__expf(sigma*irc0);
        e21 = A*(Bc*q1*q1 - 1.f)*__expf(sigma*irc1);
    } else {
        const float l0=__log2f(sigma*ir0), l1=__log2f(sigma*ir1);
        e20 = A*(Bc*exp2f(pexp*l0)-exp2f(qexp*l0))*__expf(sigma*irc0);
        e21 = A*(Bc*exp2f(pexp*l1)-exp2f(qexp*l1))*__expf(sigma*irc1);
    }
    if (!(r0<cut)) e20 = 0.f;
    if (!(r1<cut)) e21 = 0.f;

    const float tx0=g0*ux0, ty0=g0*uy0, tz0=g0*uz0;
    const float tx1=g1*ux1, ty1=g1*uy1, tz1=g1*uz1;

    m.S1 = g0+g1;
    m.G2 = g0*g0 + g1*g1;
    m.Vx = tx0+tx1;          m.Vy = ty0+ty1;          m.Vz = tz0+tz1;
    m.Mxx= tx0*ux0+tx1*ux1;  m.Myy= ty0*uy0+ty1*uy1;  m.Mzz= tz0*uz0+tz1*uz1;
    m.Mxy= tx0*uy0+tx1*uy1;  m.Mxz= tx0*uz0+tx1*uz1;  m.Myz= ty0*uz0+ty1*uz1;
    m.E2 = e20+e21;
    return m;
}

// reduce moments over the 16-lane group and evaluate closed-form energy:
// E3 = 1/2 [ Tr(M^2) - 2 c0 |V|^2 + c0^2 S1^2 - (1-c0)^2 G2 ],  returns E3 + E2/2
__device__ __forceinline__ float energy_of(const Mom& m, float cosb0) {
    const float S1  = red16(m.S1),  G2  = red16(m.G2);
    const float Vx  = red16(m.Vx),  Vy  = red16(m.Vy),  Vz  = red16(m.Vz);
    const float Mxx = red16(m.Mxx), Myy = red16(m.Myy), Mzz = red16(m.Mzz);
    const float Mxy = red16(m.Mxy), Mxz = red16(m.Mxz), Myz = red16(m.Myz);
    const float E2s = red16(m.E2);

    const float trM2 = Mxx*Mxx + Myy*Myy + Mzz*Mzz
                     + 2.f*(Mxy*Mxy + Mxz*Mxz + Myz*Myz);
    const float V2   = Vx*Vx + Vy*Vy + Vz*Vz;
    const float omc  = 1.f - cosb0;
    const float E3   = 0.5f*(trM2 - 2.f*cosb0*V2 + cosb0*cosb0*S1*S1 - omc*omc*G2);
    return E3 + 0.5f*E2s;
}

__global__ __launch_bounds__(256) void sw_energy_kernel(
    const int*   __restrict__ pc,
    const float* __restrict__ coords,
    const int*   __restrict__ nbr,
    const float* __restrict__ sA,
    const float* __restrict__ sB,
    const float* __restrict__ sP,
    const float* __restrict__ sQ,
    const float* __restrict__ sSigma,
    const float* __restrict__ sGamma,
    const float* __restrict__ sCutoff,
    const float* __restrict__ sLam,
    const float* __restrict__ sCosb0,
    double* __restrict__ ws,
    int n)
{
    __shared__ double sred[WPB];

    const int tid  = threadIdx.x;
    const int wv   = tid >> 6;
    const int lane = tid & 63;
    const int grp  = (lane >> 4) & 3;    // particle group within chain
    const int sl   = lane & 15;          // neighbor slot (handles sl and sl+16)
    const int base = blockIdx.x * PPB + wv * PPW;
    const int p0   = base + grp;         // chain 0
    const int p1   = base + 4 + grp;     // chain 1

    const float A     = *sA;
    const float Bc    = *sB;
    const float pexp  = *sP;
    const float qexp  = *sQ;
    const float sigma = *sSigma;
    const float gamma = *sGamma;
    const float cut   = *sCutoff;
    const float lam   = *sLam;
    const float cosb0 = *sCosb0;
    const float sqlam = sqrtf(lam);
    const bool fastpq = (pexp == 4.0f) && (qexp == 0.0f);

    const Mom m0 = gather2(coords, nbr, p0, sl, n, A, Bc, pexp, qexp,
                           sigma, gamma, cut, sqlam, fastpq);
    const Mom m1 = gather2(coords, nbr, p1, sl, n, A, Bc, pexp, qexp,
                           sigma, gamma, cut, sqlam, fastpq);

    const float E0 = energy_of(m0, cosb0);
    const float E1 = energy_of(m1, cosb0);

    const float w0 = (p0 < n && pc[p0] == 1) ? 1.f : 0.f;
    const float w1 = (p1 < n && pc[p1] == 1) ? 1.f : 0.f;

    // one value per 16-lane group leader, then reduce 4 leaders across the wave
    float El = (sl == 0) ? (w0 * E0 + w1 * E1) : 0.f;
    int t = __builtin_amdgcn_ds_swizzle(__float_as_int(El), 0x401F); // xor16 in 32
    El += __int_as_float(t);
    El += __shfl(El, lane ^ 32, 64);                                 // xor32

    if (lane == 0) sred[wv] = (double)El;
    __syncthreads();
    if (tid == 0) {
        ws[blockIdx.x] = sred[0] + sred[1] + sred[2] + sred[3];  // plain store
    }
}

__global__ __launch_bounds__(256) void sw_finalize_kernel(
    const double* __restrict__ ws, float* __restrict__ out, int nb)
{
    __shared__ double sred[4];
    const int tid = threadIdx.x;
    double acc = 0.0;
    for (int i = tid; i < nb; i += 256) acc += ws[i];
    for (int o = 32; o > 0; o >>= 1) acc += __shfl_down(acc, o, 64);
    if ((tid & 63) == 0) sred[tid >> 6] = acc;
    __syncthreads();
    if (tid == 0) out[0] = (float)(sred[0] + sred[1] + sred[2] + sred[3]);
}

extern "C" void kernel_launch(void* const* d_in, const int* in_sizes, int n_in,
                              void* d_out, int out_size, void* d_ws, size_t ws_size,
                              hipStream_t stream) {
    const int*   pc     = (const int*)  d_in[0];
    const float* coords = (const float*)d_in[1];
    // d_in[2] = num_neighbors (constant K=32, unused by reference math)
    const int*   nbr    = (const int*)  d_in[3];
    const float* sA     = (const float*)d_in[4];
    const float* sB     = (const float*)d_in[5];
    const float* sP     = (const float*)d_in[6];
    const float* sQ     = (const float*)d_in[7];
    const float* sSigma = (const float*)d_in[8];
    const float* sGamma = (const float*)d_in[9];
    const float* sCut   = (const float*)d_in[10];
    const float* sLam   = (const float*)d_in[11];
    const float* sCosb0 = (const float*)d_in[12];

    const int n = in_sizes[0];

    double* ws  = (double*)d_ws;
    float*  out = (float*)d_out;

    const int blocks = (n + PPB - 1) / PPB;   // 1250: every ws[b] overwritten
    sw_energy_kernel<<<blocks, 256, 0, stream>>>(
        pc, coords, nbr, sA, sB, sP, sQ, sSigma, sGamma, sCut, sLam, sCosb0,
        ws, n);

    sw_finalize_kernel<<<1, 256, 0, stream>>>(ws, out, blocks);
}